// Round 4
// baseline (365.573 us; speedup 1.0000x reference)
//
#include <hip/hip_runtime.h>

#define U_NODES 200000
#define B_ROWS  20000
#define K_S     33
#define F_DIM   256
#define E_DIM   128

typedef __bf16 bf16x8 __attribute__((ext_vector_type(8)));
typedef float  f32x4  __attribute__((ext_vector_type(4)));
typedef unsigned short ushortx8 __attribute__((ext_vector_type(8)));

__device__ __forceinline__ unsigned short f2bf(float f) {
    unsigned int u = __builtin_bit_cast(unsigned int, f);
    u += 0x7fffu + ((u >> 16) & 1u);            // round-to-nearest-even
    return (unsigned short)(u >> 16);
}
__device__ __forceinline__ float bf2f(unsigned short s) {
    return __builtin_bit_cast(float, ((unsigned int)s) << 16);
}

// ---------------------------------------------------------------------------
// One-time prep: Wt[n][k] = bf16(W[k][n]) so B-fragments are contiguous-k.
// ---------------------------------------------------------------------------
__global__ void wprep_kernel(const float* __restrict__ W, unsigned short* __restrict__ Wt) {
    int n = blockIdx.x;      // 128
    int k = threadIdx.x;     // 256
    Wt[n * F_DIM + k] = f2bf(W[(size_t)k * E_DIM + n]);
}

// ---------------------------------------------------------------------------
// MFMA bf16 GEMM: h = bf16(A @ W), fused BN column stats.
// R3 lesson: 64KB LDS halved occupancy (2 blk/CU, 19%) and latency-bound us.
// Now: W staged in TWO 32KB K-halves -> LDS 32768 -> 4 blk/CU (VGPR-capped),
// inner 4-kf chunk per half stays barrier-free; A still fragment-direct from
// global (no cross-wave reuse). XOR swizzle keeps ds_read_b128 <=2-way (free).
// ---------------------------------------------------------------------------
__global__ __launch_bounds__(256) void gemm_stats_kernel(
    const float* __restrict__ A, const unsigned short* __restrict__ Wt,
    unsigned short* __restrict__ h, float* __restrict__ gsum, float* __restrict__ gsq)
{
    __shared__ __attribute__((aligned(16))) char smem[32768];  // Ws half: [128 n][128 k] bf16

    const int t    = threadIdx.x;
    const int lane = t & 63;
    const int wv   = t >> 6;
    const int m    = lane & 15;
    const int qd   = lane >> 4;
    const int row0 = blockIdx.x * 128;

    const int r0 = row0 + wv * 32 + m;
    const int r1 = r0 + 16;
    const float* A0 = A + (size_t)min(r0, U_NODES - 1) * F_DIM + qd * 8;
    const float* A1 = A + (size_t)min(r1, U_NODES - 1) * F_DIM + qd * 8;

    f32x4 acc0[8], acc1[8];
    #pragma unroll
    for (int ct = 0; ct < 8; ++ct) {
        acc0[ct] = (f32x4){0.f, 0.f, 0.f, 0.f};
        acc1[ct] = (f32x4){0.f, 0.f, 0.f, 0.f};
    }

    #pragma unroll
    for (int half = 0; half < 2; ++half) {
        // ---- stage W half [128 n][128 k]: 2048 octets, 8 per thread ----
        if (half) __syncthreads();               // protect previous half's reads
        #pragma unroll
        for (int i = 0; i < 8; ++i) {
            int of = t + 256 * i;                // octet id 0..2047
            int n = of >> 4, o = of & 15;
            ushortx8 v = *(const ushortx8*)(Wt + n * F_DIM + half * 128 + o * 8);
            *(ushortx8*)(smem + n * 256 + (((o & 8) | ((o ^ n) & 7)) << 4)) = v;
        }
        __syncthreads();
        // ---- 4 barrier-free k-chunks of 32 ----
        #pragma unroll
        for (int kf = 0; kf < 4; ++kf) {
            const float* a0p = A0 + half * 128 + kf * 32;
            const float* a1p = A1 + half * 128 + kf * 32;
            float a0f[8], a1f[8];
            *(float4*)&a0f[0] = *(const float4*)(a0p);
            *(float4*)&a0f[4] = *(const float4*)(a0p + 4);
            *(float4*)&a1f[0] = *(const float4*)(a1p);
            *(float4*)&a1f[4] = *(const float4*)(a1p + 4);
            ushortx8 u0, u1;
            #pragma unroll
            for (int j = 0; j < 8; ++j) { u0[j] = f2bf(a0f[j]); u1[j] = f2bf(a1f[j]); }
            bf16x8 a0 = __builtin_bit_cast(bf16x8, u0);
            bf16x8 a1 = __builtin_bit_cast(bf16x8, u1);
            int o = kf * 4 + qd;                 // octet within half
            #pragma unroll
            for (int ct = 0; ct < 8; ++ct) {
                int n = ct * 16 + m;
                bf16x8 b = *(const bf16x8*)(smem + n * 256 + (((o & 8) | ((o ^ n) & 7)) << 4));
                acc0[ct] = __builtin_amdgcn_mfma_f32_16x16x32_bf16(a0, b, acc0[ct], 0, 0, 0);
                acc1[ct] = __builtin_amdgcn_mfma_f32_16x16x32_bf16(a1, b, acc1[ct], 0, 0, 0);
            }
        }
    }
    __syncthreads();

    // ---- fused BN stats (D layout m89: col=lane&15, row=(lane>>4)*4+reg) ----
    const bool full = (row0 + 128) <= U_NODES;
    float s[8], sq[8];
    #pragma unroll
    for (int ct = 0; ct < 8; ++ct) {
        float ss = 0.f, qq = 0.f;
        #pragma unroll
        for (int v = 0; v < 4; ++v) {
            float x0 = acc0[ct][v];
            float x1 = acc1[ct][v];
            if (full || (row0 + wv * 32 + qd * 4 + v) < U_NODES)      { ss += x0; qq += x0 * x0; }
            if (full || (row0 + wv * 32 + 16 + qd * 4 + v) < U_NODES) { ss += x1; qq += x1 * x1; }
        }
        s[ct] = ss; sq[ct] = qq;
    }
    float* red = (float*)smem;   // [16][128]
    int rq = wv * 4 + qd;
    #pragma unroll
    for (int ct = 0; ct < 8; ++ct) red[rq * 128 + ct * 16 + m] = s[ct];
    __syncthreads();
    if (t < 128) {
        float tot = 0.f;
        #pragma unroll
        for (int i = 0; i < 16; ++i) tot += red[i * 128 + t];
        atomicAdd(&gsum[t], tot);
    }
    __syncthreads();
    #pragma unroll
    for (int ct = 0; ct < 8; ++ct) red[rq * 128 + ct * 16 + m] = sq[ct];
    __syncthreads();
    if (t < 128) {
        float tot = 0.f;
        #pragma unroll
        for (int i = 0; i < 16; ++i) tot += red[i * 128 + t];
        atomicAdd(&gsq[t], tot);
    }
    __syncthreads();

    // ---- h store: acc layout -> per-wave LDS transpose -> coalesced stores ----
    unsigned short* tb = (unsigned short*)(smem + wv * 8192);   // [32][128] per wave
    #pragma unroll
    for (int ct = 0; ct < 8; ++ct)
        #pragma unroll
        for (int v = 0; v < 4; ++v) {
            tb[(qd * 4 + v) * 128 + ct * 16 + m]      = f2bf(acc0[ct][v]);
            tb[(16 + qd * 4 + v) * 128 + ct * 16 + m] = f2bf(acc1[ct][v]);
        }
    #pragma unroll
    for (int i = 0; i < 8; ++i) {
        int idx = lane + 64 * i;            // 0..511
        int r = idx >> 4, c8 = (idx & 15) * 8;
        int gr = row0 + wv * 32 + r;
        if (gr < U_NODES)
            *(ushortx8*)(h + (size_t)gr * E_DIM + c8) = *(const ushortx8*)(tb + r * 128 + c8);
    }
}

// ---------------------------------------------------------------------------
// Fold BN stats + gamma/beta into per-column scale/shift.
// ---------------------------------------------------------------------------
__global__ void finalize_kernel(const float* __restrict__ gsum, const float* __restrict__ gsq,
                                const float* __restrict__ gamma, const float* __restrict__ beta,
                                float* __restrict__ scale, float* __restrict__ shift)
{
    int e = threadIdx.x;
    float mu  = gsum[e] * (1.f / U_NODES);
    float var = gsq[e] * (1.f / U_NODES) - mu * mu;
    float inv = rsqrtf(var + 1e-5f);
    float sc  = gamma[e] * inv;
    scale[e] = sc;
    shift[e] = beta[e] - sc * mu;
}

// ---------------------------------------------------------------------------
// Activation pass: h <- bf16(tanh(h*scale + shift)), in place, ONCE per
// unique row (200k) instead of once per sample (660k) — kills the 3.3x
// redundant transcendental work that was fused into the gather.
// Thread's column group is fixed (t&15)*8 so scale/shift live in 16 regs.
// ---------------------------------------------------------------------------
__global__ __launch_bounds__(256) void act_kernel(
    unsigned short* __restrict__ h,
    const float* __restrict__ scale, const float* __restrict__ shift)
{
    const int t = threadIdx.x;
    const int g = t & 15;
    float scv[8], shv[8];
    *(float4*)&scv[0] = *(const float4*)(scale + g * 8);
    *(float4*)&scv[4] = *(const float4*)(scale + g * 8 + 4);
    *(float4*)&shv[0] = *(const float4*)(shift + g * 8);
    *(float4*)&shv[4] = *(const float4*)(shift + g * 8 + 4);

    const int NCH = U_NODES * 16;                     // ushort8 chunks (16 per row)
    for (int c = blockIdx.x * 256 + t; c < NCH; c += gridDim.x * 256) {
        ushortx8* p = (ushortx8*)(h + (size_t)c * 8);
        ushortx8 v = *p;
        #pragma unroll
        for (int j = 0; j < 8; ++j) {
            float x  = bf2f(v[j]) * scv[j] + shv[j];
            float tn = 1.f - 2.f * __builtin_amdgcn_rcpf(__expf(2.f * x) + 1.f);
            v[j] = f2bf(tn);
        }
        *p = v;
    }
}

// ---------------------------------------------------------------------------
// Pure gather-mean: out[b] = mean_k h[idx[b,k]]. No transcendentals left.
// 16 lanes x ushort8 per row, 16 rows per 256-thr block, K fully unrolled;
// launch_bounds(...,4) caps VGPR at 128 so >=16 waves/CU hide L3 latency.
// ---------------------------------------------------------------------------
__global__ __launch_bounds__(256, 4) void gather_kernel(
    const unsigned short* __restrict__ h, const int* __restrict__ sidx_g,
    float* __restrict__ out)
{
    __shared__ int sl[16 * K_S];
    const int t  = threadIdx.x;
    const int g  = t & 15;          // col group: cols g*8..g*8+7
    const int r  = t >> 4;          // row within block
    const int b0 = blockIdx.x * 16;
    for (int i = t; i < 16 * K_S; i += 256) sl[i] = sidx_g[(size_t)b0 * K_S + i];
    __syncthreads();

    float acc[8] = {0.f, 0.f, 0.f, 0.f, 0.f, 0.f, 0.f, 0.f};
    #pragma unroll
    for (int k = 0; k < K_S; ++k) {
        int idx = sl[r * K_S + k];
        ushortx8 v = *(const ushortx8*)(h + (size_t)idx * E_DIM + g * 8);
        #pragma unroll
        for (int j = 0; j < 8; ++j) acc[j] += bf2f(v[j]);
    }
    float* op = out + (size_t)(b0 + r) * E_DIM + g * 8;
    *(float4*)(op)     = make_float4(acc[0] * (1.f / K_S), acc[1] * (1.f / K_S),
                                     acc[2] * (1.f / K_S), acc[3] * (1.f / K_S));
    *(float4*)(op + 4) = make_float4(acc[4] * (1.f / K_S), acc[5] * (1.f / K_S),
                                     acc[6] * (1.f / K_S), acc[7] * (1.f / K_S));
}

// ---------------------------------------------------------------------------
extern "C" void kernel_launch(void* const* d_in, const int* in_sizes, int n_in,
                              void* d_out, int out_size, void* d_ws, size_t ws_size,
                              hipStream_t stream) {
    const float* features = (const float*)d_in[0];
    const float* W        = (const float*)d_in[1];
    // d_in[2] = bias — provably cancels inside BatchNorm; unused.
    const float* gamma    = (const float*)d_in[3];
    const float* beta     = (const float*)d_in[4];
    const int*   sample   = (const int*)d_in[5];
    float* out = (float*)d_out;

    // ws layout: gsum[128] gsq[128] scale[128] shift[128] | Wt[128*256 bf16] | h[U*128 bf16]
    float* gsum  = (float*)d_ws;
    float* gsq   = gsum + 128;
    float* scale = gsq + 128;
    float* shift = scale + 128;
    unsigned short* Wt = (unsigned short*)(shift + 128);
    unsigned short* h  = Wt + 128 * 256;

    hipMemsetAsync(gsum, 0, 2 * 128 * sizeof(float), stream);
    wprep_kernel<<<128, 256, 0, stream>>>(W, Wt);
    gemm_stats_kernel<<<(U_NODES + 127) / 128, 256, 0, stream>>>(features, Wt, h, gsum, gsq);
    finalize_kernel<<<1, 128, 0, stream>>>(gsum, gsq, gamma, beta, scale, shift);
    act_kernel<<<1024, 256, 0, stream>>>(h, scale, shift);
    gather_kernel<<<B_ROWS / 16, 256, 0, stream>>>(h, sample, out);
}

// Round 5
// 355.416 us; speedup vs baseline: 1.0286x; 1.0286x over previous
//
#include <hip/hip_runtime.h>

#define U_NODES 200000
#define B_ROWS  20000
#define K_S     33
#define F_DIM   256
#define E_DIM   128
#define NPART   128     // stats partial buffers (kills same-address atomic contention)

typedef __bf16 bf16x8 __attribute__((ext_vector_type(8)));
typedef float  f32x4  __attribute__((ext_vector_type(4)));
typedef unsigned short ushortx8 __attribute__((ext_vector_type(8)));

__device__ __forceinline__ unsigned short f2bf(float f) {
    unsigned int u = __builtin_bit_cast(unsigned int, f);
    u += 0x7fffu + ((u >> 16) & 1u);            // round-to-nearest-even
    return (unsigned short)(u >> 16);
}
__device__ __forceinline__ float bf2f(unsigned short s) {
    return __builtin_bit_cast(float, ((unsigned int)s) << 16);
}

// ---------------------------------------------------------------------------
// One-time prep: Wt[n][k] = bf16(W[k][n]) so B-fragments are contiguous-k.
// ---------------------------------------------------------------------------
__global__ void wprep_kernel(const float* __restrict__ W, unsigned short* __restrict__ Wt) {
    int n = blockIdx.x;      // 128
    int k = threadIdx.x;     // 256
    Wt[n * F_DIM + k] = f2bf(W[(size_t)k * E_DIM + n]);
}

// ---------------------------------------------------------------------------
// MFMA bf16 GEMM: h = bf16(A @ W), fused BN column stats.
// R4 post-mortem: the gemm's hidden ~80us was 1563 blocks x 256 atomicAdds
// to the SAME 256 addresses (all pipes idle during the drain). Fix: stats go
// to 128 partial rows part[blockIdx&127][256] -> ~12 collisions/address.
// K-loop unchanged from R4 (W staged in two 32KB halves, A fragment-direct).
// ---------------------------------------------------------------------------
__global__ __launch_bounds__(256) void gemm_stats_kernel(
    const float* __restrict__ A, const unsigned short* __restrict__ Wt,
    unsigned short* __restrict__ h, float* __restrict__ part)
{
    __shared__ __attribute__((aligned(16))) char smem[32768];  // Ws half: [128 n][128 k] bf16

    const int t    = threadIdx.x;
    const int lane = t & 63;
    const int wv   = t >> 6;
    const int m    = lane & 15;
    const int qd   = lane >> 4;
    const int row0 = blockIdx.x * 128;

    const int r0 = row0 + wv * 32 + m;
    const int r1 = r0 + 16;
    const float* A0 = A + (size_t)min(r0, U_NODES - 1) * F_DIM + qd * 8;
    const float* A1 = A + (size_t)min(r1, U_NODES - 1) * F_DIM + qd * 8;

    f32x4 acc0[8], acc1[8];
    #pragma unroll
    for (int ct = 0; ct < 8; ++ct) {
        acc0[ct] = (f32x4){0.f, 0.f, 0.f, 0.f};
        acc1[ct] = (f32x4){0.f, 0.f, 0.f, 0.f};
    }

    #pragma unroll
    for (int half = 0; half < 2; ++half) {
        // ---- stage W half [128 n][128 k]: 2048 octets, 8 per thread ----
        if (half) __syncthreads();               // protect previous half's reads
        #pragma unroll
        for (int i = 0; i < 8; ++i) {
            int of = t + 256 * i;                // octet id 0..2047
            int n = of >> 4, o = of & 15;
            ushortx8 v = *(const ushortx8*)(Wt + n * F_DIM + half * 128 + o * 8);
            *(ushortx8*)(smem + n * 256 + (((o & 8) | ((o ^ n) & 7)) << 4)) = v;
        }
        __syncthreads();
        // ---- 4 barrier-free k-chunks of 32 ----
        #pragma unroll
        for (int kf = 0; kf < 4; ++kf) {
            const float* a0p = A0 + half * 128 + kf * 32;
            const float* a1p = A1 + half * 128 + kf * 32;
            float a0f[8], a1f[8];
            *(float4*)&a0f[0] = *(const float4*)(a0p);
            *(float4*)&a0f[4] = *(const float4*)(a0p + 4);
            *(float4*)&a1f[0] = *(const float4*)(a1p);
            *(float4*)&a1f[4] = *(const float4*)(a1p + 4);
            ushortx8 u0, u1;
            #pragma unroll
            for (int j = 0; j < 8; ++j) { u0[j] = f2bf(a0f[j]); u1[j] = f2bf(a1f[j]); }
            bf16x8 a0 = __builtin_bit_cast(bf16x8, u0);
            bf16x8 a1 = __builtin_bit_cast(bf16x8, u1);
            int o = kf * 4 + qd;                 // octet within half
            #pragma unroll
            for (int ct = 0; ct < 8; ++ct) {
                int n = ct * 16 + m;
                bf16x8 b = *(const bf16x8*)(smem + n * 256 + (((o & 8) | ((o ^ n) & 7)) << 4));
                acc0[ct] = __builtin_amdgcn_mfma_f32_16x16x32_bf16(a0, b, acc0[ct], 0, 0, 0);
                acc1[ct] = __builtin_amdgcn_mfma_f32_16x16x32_bf16(a1, b, acc1[ct], 0, 0, 0);
            }
        }
    }
    __syncthreads();

    // ---- fused BN stats (D layout m89: col=lane&15, row=(lane>>4)*4+reg) ----
    const bool full = (row0 + 128) <= U_NODES;
    float s[8], sq[8];
    #pragma unroll
    for (int ct = 0; ct < 8; ++ct) {
        float ss = 0.f, qq = 0.f;
        #pragma unroll
        for (int v = 0; v < 4; ++v) {
            float x0 = acc0[ct][v];
            float x1 = acc1[ct][v];
            if (full || (row0 + wv * 32 + qd * 4 + v) < U_NODES)      { ss += x0; qq += x0 * x0; }
            if (full || (row0 + wv * 32 + 16 + qd * 4 + v) < U_NODES) { ss += x1; qq += x1 * x1; }
        }
        s[ct] = ss; sq[ct] = qq;
    }
    // merged [16 rq][256] reduction buffer: cols 0..127 = sum, 128..255 = sumsq
    float* red = (float*)smem;
    int rq = wv * 4 + qd;
    #pragma unroll
    for (int ct = 0; ct < 8; ++ct) {
        red[rq * 256 + ct * 16 + m]       = s[ct];
        red[rq * 256 + 128 + ct * 16 + m] = sq[ct];
    }
    __syncthreads();
    {
        float tot = 0.f;
        #pragma unroll
        for (int i = 0; i < 16; ++i) tot += red[i * 256 + t];
        atomicAdd(&part[(blockIdx.x & (NPART - 1)) * 256 + t], tot);
    }
    __syncthreads();

    // ---- h store: acc layout -> per-wave LDS transpose -> coalesced stores ----
    unsigned short* tb = (unsigned short*)(smem + wv * 8192);   // [32][128] per wave
    #pragma unroll
    for (int ct = 0; ct < 8; ++ct)
        #pragma unroll
        for (int v = 0; v < 4; ++v) {
            tb[(qd * 4 + v) * 128 + ct * 16 + m]      = f2bf(acc0[ct][v]);
            tb[(16 + qd * 4 + v) * 128 + ct * 16 + m] = f2bf(acc1[ct][v]);
        }
    __syncthreads();
    #pragma unroll
    for (int i = 0; i < 8; ++i) {
        int idx = lane + 64 * i;            // 0..511
        int r = idx >> 4, c8 = (idx & 15) * 8;
        int gr = row0 + wv * 32 + r;
        if (gr < U_NODES)
            *(ushortx8*)(h + (size_t)gr * E_DIM + c8) = *(const ushortx8*)(tb + r * 128 + c8);
    }
}

// ---------------------------------------------------------------------------
// Reduce 128 stat partials; fold BN stats + gamma/beta into scale/shift.
// ---------------------------------------------------------------------------
__global__ void finalize_kernel(const float* __restrict__ part,
                                const float* __restrict__ gamma, const float* __restrict__ beta,
                                float* __restrict__ scale, float* __restrict__ shift)
{
    int e = threadIdx.x;        // 0..127
    float sum = 0.f, sq = 0.f;
    for (int p = 0; p < NPART; ++p) {
        sum += part[p * 256 + e];
        sq  += part[p * 256 + 128 + e];
    }
    float mu  = sum * (1.f / U_NODES);
    float var = sq * (1.f / U_NODES) - mu * mu;
    float inv = rsqrtf(var + 1e-5f);
    float sc  = gamma[e] * inv;
    scale[e] = sc;
    shift[e] = beta[e] - sc * mu;
}

// ---------------------------------------------------------------------------
// Gather + BN + tanh + mean over K=33 (tanh fused here: R4 proved the split
// act pass was pure extra traffic — transcendentals hide under the gather's
// memory latency). 16 lanes x ushort8 per row, 16 rows per 256-thr block.
// ---------------------------------------------------------------------------
__global__ __launch_bounds__(256, 4) void gather_kernel(
    const unsigned short* __restrict__ h, const int* __restrict__ sidx_g,
    const float* __restrict__ scale, const float* __restrict__ shift,
    float* __restrict__ out)
{
    __shared__ int sl[16 * K_S];
    const int t  = threadIdx.x;
    const int g  = t & 15;          // col group: cols g*8..g*8+7
    const int r  = t >> 4;          // row within block
    const int b0 = blockIdx.x * 16;
    for (int i = t; i < 16 * K_S; i += 256) sl[i] = sidx_g[(size_t)b0 * K_S + i];
    float scv[8], shv[8];
    *(float4*)&scv[0] = *(const float4*)(scale + g * 8);
    *(float4*)&scv[4] = *(const float4*)(scale + g * 8 + 4);
    *(float4*)&shv[0] = *(const float4*)(shift + g * 8);
    *(float4*)&shv[4] = *(const float4*)(shift + g * 8 + 4);
    __syncthreads();

    float acc[8] = {0.f, 0.f, 0.f, 0.f, 0.f, 0.f, 0.f, 0.f};
    #pragma unroll
    for (int k = 0; k < K_S; ++k) {
        int idx = sl[r * K_S + k];
        ushortx8 v = *(const ushortx8*)(h + (size_t)idx * E_DIM + g * 8);
        #pragma unroll
        for (int j = 0; j < 8; ++j) {
            float x = bf2f(v[j]) * scv[j] + shv[j];
            acc[j] += 1.f - 2.f * __builtin_amdgcn_rcpf(__expf(2.f * x) + 1.f);  // tanh
        }
    }
    float* op = out + (size_t)(b0 + r) * E_DIM + g * 8;
    *(float4*)(op)     = make_float4(acc[0] * (1.f / K_S), acc[1] * (1.f / K_S),
                                     acc[2] * (1.f / K_S), acc[3] * (1.f / K_S));
    *(float4*)(op + 4) = make_float4(acc[4] * (1.f / K_S), acc[5] * (1.f / K_S),
                                     acc[6] * (1.f / K_S), acc[7] * (1.f / K_S));
}

// ---------------------------------------------------------------------------
extern "C" void kernel_launch(void* const* d_in, const int* in_sizes, int n_in,
                              void* d_out, int out_size, void* d_ws, size_t ws_size,
                              hipStream_t stream) {
    const float* features = (const float*)d_in[0];
    const float* W        = (const float*)d_in[1];
    // d_in[2] = bias — provably cancels inside BatchNorm; unused.
    const float* gamma    = (const float*)d_in[3];
    const float* beta     = (const float*)d_in[4];
    const int*   sample   = (const int*)d_in[5];
    float* out = (float*)d_out;

    // ws layout: part[128][256] | scale[128] shift[128] | Wt[128*256 bf16] | h[U*128 bf16]
    float* part  = (float*)d_ws;
    float* scale = part + NPART * 256;
    float* shift = scale + 128;
    unsigned short* Wt = (unsigned short*)(shift + 128);
    unsigned short* h  = Wt + 128 * 256;

    hipMemsetAsync(part, 0, NPART * 256 * sizeof(float), stream);
    wprep_kernel<<<128, 256, 0, stream>>>(W, Wt);
    gemm_stats_kernel<<<(U_NODES + 127) / 128, 256, 0, stream>>>(features, Wt, h, part);
    finalize_kernel<<<1, 128, 0, stream>>>(part, gamma, beta, scale, shift);
    gather_kernel<<<B_ROWS / 16, 256, 0, stream>>>(h, sample, scale, shift, out);
}

// Round 6
// 350.704 us; speedup vs baseline: 1.0424x; 1.0134x over previous
//
#include <hip/hip_runtime.h>

#define U_NODES 200000
#define B_ROWS  20000
#define K_S     33
#define F_DIM   256
#define E_DIM   128
#define NPART   128

typedef __bf16 bf16x8 __attribute__((ext_vector_type(8)));
typedef float  f32x4  __attribute__((ext_vector_type(4)));
typedef unsigned short ushortx8 __attribute__((ext_vector_type(8)));

__device__ __forceinline__ unsigned short f2bf(float f) {
    unsigned int u = __builtin_bit_cast(unsigned int, f);
    u += 0x7fffu + ((u >> 16) & 1u);            // round-to-nearest-even
    return (unsigned short)(u >> 16);
}
__device__ __forceinline__ float bf2f(unsigned short s) {
    return __builtin_bit_cast(float, ((unsigned int)s) << 16);
}

// ---------------------------------------------------------------------------
// One-time prep: Wt[n][k] = bf16(W[k][n]) so B-fragments are contiguous-k.
// ---------------------------------------------------------------------------
__global__ void wprep_kernel(const float* __restrict__ W, unsigned short* __restrict__ Wt) {
    int n = blockIdx.x;      // 128
    int k = threadIdx.x;     // 256
    Wt[n * F_DIM + k] = f2bf(W[(size_t)k * E_DIM + n]);
}

// ---------------------------------------------------------------------------
// MFMA bf16 GEMM, R6: ALL of A in registers, ONE round trip.
// R5 post-mortem: gemm stuck ~110us across all structures with every pipe
// <10% busy -> load-pipeline-depth-bound (~1 load-group in flight/wave at
// VGPR=100). Fix: wave owns 16 rows; each thread issues its 16 upfront
// dwordx4 loads covering its ENTIRE K=256 A-slice (64 VGPR transient),
// cvt->bf16 (32 VGPR), then the whole MFMA loop runs with ZERO global loads
// (W from 32KB LDS halves). 64 rows/block, grid 3125 = exact (no tail).
// ---------------------------------------------------------------------------
__global__ __launch_bounds__(256, 4) void gemm_stats_kernel(
    const float* __restrict__ A, const unsigned short* __restrict__ Wt,
    unsigned short* __restrict__ h, float* __restrict__ part)
{
    __shared__ __attribute__((aligned(16))) char smem[32768];  // W half: [128 n][128 k] bf16

    const int t    = threadIdx.x;
    const int lane = t & 63;
    const int wv   = t >> 6;
    const int m    = lane & 15;
    const int qd   = lane >> 4;
    const int row0 = blockIdx.x * 64;
    const int row  = row0 + wv * 16 + m;           // exact: 3125*64 == 200000

    // ---- 16 upfront A-loads: this thread's whole K-slice (rows split by qd) ----
    const float* Ap = A + (size_t)row * F_DIM + qd * 8;
    float a[8][8];
    #pragma unroll
    for (int kf = 0; kf < 8; ++kf) {
        *(float4*)&a[kf][0] = *(const float4*)(Ap + kf * 32);
        *(float4*)&a[kf][4] = *(const float4*)(Ap + kf * 32 + 4);
    }

    // ---- stage W half 0 (loads stream behind the A-loads) ----
    #pragma unroll
    for (int i = 0; i < 8; ++i) {
        int of = t + 256 * i, n = of >> 4, o = of & 15;
        ushortx8 v = *(const ushortx8*)(Wt + n * F_DIM + o * 8);
        *(ushortx8*)(smem + n * 256 + (((o & 8) | ((o ^ n) & 7)) << 4)) = v;
    }

    // ---- cvt all A to bf16 fragments; a[] dies here ----
    bf16x8 af[8];
    #pragma unroll
    for (int kf = 0; kf < 8; ++kf) {
        ushortx8 u;
        #pragma unroll
        for (int j = 0; j < 8; ++j) u[j] = f2bf(a[kf][j]);
        af[kf] = __builtin_bit_cast(bf16x8, u);
    }

    f32x4 acc[8];
    #pragma unroll
    for (int ct = 0; ct < 8; ++ct) acc[ct] = (f32x4){0.f, 0.f, 0.f, 0.f};

    __syncthreads();
    // ---- compute half 0 (kf 0..3): zero global loads ----
    #pragma unroll
    for (int kfl = 0; kfl < 4; ++kfl) {
        int o = kfl * 4 + qd;
        #pragma unroll
        for (int ct = 0; ct < 8; ++ct) {
            int n = ct * 16 + m;
            bf16x8 b = *(const bf16x8*)(smem + n * 256 + (((o & 8) | ((o ^ n) & 7)) << 4));
            acc[ct] = __builtin_amdgcn_mfma_f32_16x16x32_bf16(af[kfl], b, acc[ct], 0, 0, 0);
        }
    }
    // ---- stage W half 1 ----
    ushortx8 wreg[8];
    #pragma unroll
    for (int i = 0; i < 8; ++i) {
        int of = t + 256 * i, n = of >> 4, o = of & 15;
        wreg[i] = *(const ushortx8*)(Wt + n * F_DIM + 128 + o * 8);
    }
    __syncthreads();
    #pragma unroll
    for (int i = 0; i < 8; ++i) {
        int of = t + 256 * i, n = of >> 4, o = of & 15;
        *(ushortx8*)(smem + n * 256 + (((o & 8) | ((o ^ n) & 7)) << 4)) = wreg[i];
    }
    __syncthreads();
    // ---- compute half 1 (kf 4..7) ----
    #pragma unroll
    for (int kfl = 0; kfl < 4; ++kfl) {
        int o = kfl * 4 + qd;
        #pragma unroll
        for (int ct = 0; ct < 8; ++ct) {
            int n = ct * 16 + m;
            bf16x8 b = *(const bf16x8*)(smem + n * 256 + (((o & 8) | ((o ^ n) & 7)) << 4));
            acc[ct] = __builtin_amdgcn_mfma_f32_16x16x32_bf16(af[4 + kfl], b, acc[ct], 0, 0, 0);
        }
    }
    __syncthreads();   // LDS reads done; reuse as reduction buffer

    // ---- BN stats (D layout m89: col = ct*16+m, row-in-tile = qd*4+v) ----
    float* red = (float*)smem;          // [16 rq][256]: cols 0..127 sum, 128..255 sumsq
    int rq = wv * 4 + qd;
    #pragma unroll
    for (int ct = 0; ct < 8; ++ct) {
        float ss = 0.f, qq = 0.f;
        #pragma unroll
        for (int v = 0; v < 4; ++v) { float x = acc[ct][v]; ss += x; qq += x * x; }
        red[rq * 256 + ct * 16 + m]       = ss;
        red[rq * 256 + 128 + ct * 16 + m] = qq;
    }
    __syncthreads();
    {
        float tot = 0.f;
        #pragma unroll
        for (int i = 0; i < 16; ++i) tot += red[i * 256 + t];
        atomicAdd(&part[(blockIdx.x & (NPART - 1)) * 256 + t], tot);
    }
    __syncthreads();

    // ---- h store: acc -> per-wave LDS transpose -> coalesced bf16x8 stores ----
    unsigned short* tb = (unsigned short*)(smem + wv * 4096);   // [16][128] per wave
    #pragma unroll
    for (int ct = 0; ct < 8; ++ct)
        #pragma unroll
        for (int v = 0; v < 4; ++v)
            tb[(qd * 4 + v) * 128 + ct * 16 + m] = f2bf(acc[ct][v]);
    __syncthreads();
    #pragma unroll
    for (int i = 0; i < 4; ++i) {
        int idx = lane + 64 * i;            // 0..255
        int r = idx >> 4, c8 = (idx & 15) * 8;
        int gr = row0 + wv * 16 + r;
        *(ushortx8*)(h + (size_t)gr * E_DIM + c8) = *(const ushortx8*)(tb + r * 128 + c8);
    }
}

// ---------------------------------------------------------------------------
// Reduce stat partials; fold BN stats + gamma/beta into scale/shift.
// ---------------------------------------------------------------------------
__global__ void finalize_kernel(const float* __restrict__ part,
                                const float* __restrict__ gamma, const float* __restrict__ beta,
                                float* __restrict__ scale, float* __restrict__ shift)
{
    int e = threadIdx.x;        // 0..127
    float sum = 0.f, sq = 0.f;
    for (int p = 0; p < NPART; ++p) {
        sum += part[p * 256 + e];
        sq  += part[p * 256 + 128 + e];
    }
    float mu  = sum * (1.f / U_NODES);
    float var = sq * (1.f / U_NODES) - mu * mu;
    float inv = rsqrtf(var + 1e-5f);
    float sc  = gamma[e] * inv;
    scale[e] = sc;
    shift[e] = beta[e] - sc * mu;
}

// ---------------------------------------------------------------------------
// Gather + BN + tanh + mean over K=33. R6: uint2 (8B = 4 bf16 cols) per lane,
// 32 lanes per row, 2 rows per wave -> 33 loads x 2 VGPR = 66 in flight per
// thread (fits under the 128-VGPR cap; R5's ushort8 needed 132 -> compiler
// serialized). 8 rows / 256-thr block.
// ---------------------------------------------------------------------------
__global__ __launch_bounds__(256, 4) void gather_kernel(
    const unsigned short* __restrict__ h, const int* __restrict__ sidx_g,
    const float* __restrict__ scale, const float* __restrict__ shift,
    float* __restrict__ out)
{
    __shared__ int sl[8 * K_S];
    const int t    = threadIdx.x;
    const int lane = t & 63;
    const int wv   = t >> 6;
    const int sub  = lane >> 5;         // half-wave -> row select
    const int e    = lane & 31;         // col group: cols e*4 .. e*4+3
    const int rloc = wv * 2 + sub;      // 0..7
    const int b0   = blockIdx.x * 8;
    for (int i = t; i < 8 * K_S; i += 256) sl[i] = sidx_g[(size_t)b0 * K_S + i];
    float scv[4], shv[4];
    *(float4*)scv = *(const float4*)(scale + e * 4);
    *(float4*)shv = *(const float4*)(shift + e * 4);
    __syncthreads();

    float acc[4] = {0.f, 0.f, 0.f, 0.f};
    #pragma unroll
    for (int k = 0; k < K_S; ++k) {
        int idx = sl[rloc * K_S + k];
        uint2 v = *(const uint2*)(h + (size_t)idx * E_DIM + e * 4);
        unsigned short c[4] = { (unsigned short)(v.x & 0xffff), (unsigned short)(v.x >> 16),
                                (unsigned short)(v.y & 0xffff), (unsigned short)(v.y >> 16) };
        #pragma unroll
        for (int j = 0; j < 4; ++j) {
            float x = bf2f(c[j]) * scv[j] + shv[j];
            acc[j] += 1.f - 2.f * __builtin_amdgcn_rcpf(__expf(2.f * x) + 1.f);  // tanh
        }
    }
    *(float4*)(out + (size_t)(b0 + rloc) * E_DIM + e * 4) =
        make_float4(acc[0] * (1.f / K_S), acc[1] * (1.f / K_S),
                    acc[2] * (1.f / K_S), acc[3] * (1.f / K_S));
}

// ---------------------------------------------------------------------------
extern "C" void kernel_launch(void* const* d_in, const int* in_sizes, int n_in,
                              void* d_out, int out_size, void* d_ws, size_t ws_size,
                              hipStream_t stream) {
    const float* features = (const float*)d_in[0];
    const float* W        = (const float*)d_in[1];
    // d_in[2] = bias — provably cancels inside BatchNorm; unused.
    const float* gamma    = (const float*)d_in[3];
    const float* beta     = (const float*)d_in[4];
    const int*   sample   = (const int*)d_in[5];
    float* out = (float*)d_out;

    // ws layout: part[128][256] | scale[128] shift[128] | Wt[128*256 bf16] | h[U*128 bf16]
    float* part  = (float*)d_ws;
    float* scale = part + NPART * 256;
    float* shift = scale + 128;
    unsigned short* Wt = (unsigned short*)(shift + 128);
    unsigned short* h  = Wt + 128 * 256;

    hipMemsetAsync(part, 0, NPART * 256 * sizeof(float), stream);
    wprep_kernel<<<128, 256, 0, stream>>>(W, Wt);
    gemm_stats_kernel<<<U_NODES / 64, 256, 0, stream>>>(features, Wt, h, part);
    finalize_kernel<<<1, 128, 0, stream>>>(part, gamma, beta, scale, shift);
    gather_kernel<<<B_ROWS / 8, 256, 0, stream>>>(h, sample, scale, shift, out);
}